// Round 8
// baseline (114.443 us; speedup 1.0000x reference)
//
#include <hip/hip_runtime.h>
#include <math.h>

// Problem constants (match reference)
#define NANG   4
#define NELEM  128
#define NSAMP  2048
#define NZ     192
#define NX     192
#define NPIX   (NZ * NX)
#define ECHUNK 32                 // elements per wave-chunk (threadIdx.y)
#define XT     16                 // tile: 16 pixels in x ...
#define ZT     4                  // ... by 4 rows in z
#define NXT    (NX / XT)          // 12
#define NZT    (NZ / ZT)          // 48

constexpr float C_SOUND = 1540.0f;
constexpr float FS      = 20832000.0f;
constexpr float FDEMOD  = 5208000.0f;
constexpr float FS_C    = FS / C_SOUND;      // samples per meter

// R8: ANGLE FACTORIZATION. delays = txdel(p,a) + rxdel(p,e) and
// theta = 2pi*(0.25*delays - zrev) splits into R(p,e) * P_tx(p,a):
//   - ONE sqrt + ONE sincos per (pixel,element) pair, shared by all 4 angles
//     (4x fewer transcendentals than R4-R7's per-triple sincos)
//   - tx apodization folded into P_tx (zeroed), rx mask zeroes R
//   - per angle: lerp gather + one complex mul + complex MAC
// Waves: 576 tiles x 4 element-chunks(32) = 2304 fat waves (4x fewer
// preambles). 8 independent dwordx2 loads per pair-iter + unroll-2 gives
// in-wave ILP for latency hiding at ~2.25 waves/SIMD.
//
// Carried facts (verified across passing rounds, absmax 0.25):
//  - rx apod == (z > 2|x-ex|) exactly; block-uniform e-interval skip
//  - delays in [26,1520] -> no sample-index clamp
//  - v_sin/v_cos take revolutions; args reduced mod 1 -> in [0,1)
//  - reads only d_in; memset + coalesced atomicAdd on d_out (replay-proven)
__global__ __launch_bounds__(256) void das_pw_kernel(
    const float* __restrict__ idata,     // [NANG][NELEM][NSAMP]
    const float* __restrict__ qdata,     // [NANG][NELEM][NSAMP]
    const float* __restrict__ grid,      // [NPIX][3]
    const float* __restrict__ angles,    // [NANG]
    const float* __restrict__ ele_pos,   // [NELEM][3]
    const float* __restrict__ time_zero, // [NANG]
    float* __restrict__ out)             // [2*NPIX]: idas then qdas (pre-zeroed)
{
    const int lane = threadIdx.x;        // 0..63 : pixel within 16x4 tile
    const int cy   = threadIdx.y;        // 0..3  : 32-element chunk (per wave)

    const int x0c = ((int)blockIdx.x % NXT) * XT;
    const int z0r = ((int)blockIdx.x / NXT) * ZT;

    // Block-uniform geometry (uniform addresses -> scalar loads)
    const float ex0    = ele_pos[0];
    const float inv_pe = 1.0f / (ele_pos[3] - ex0);
    const float xlimN  = ele_pos[3 * (NELEM - 1)];
    const float xminT  = grid[3 * (z0r * NX + x0c)];
    const float xmaxT  = grid[3 * (z0r * NX + x0c + XT - 1)];
    const float zmaxT  = grid[3 * ((z0r + ZT - 1) * NX + x0c) + 2];
    const float half   = 0.5f * zmaxT;

    int e_lo = (int)floorf((xminT - half - ex0) * inv_pe);      // conservative
    int e_hi = (int)ceilf ((xmaxT + half - ex0) * inv_pe) + 1;  // exclusive
    e_lo = max(e_lo, cy * ECHUNK);
    e_hi = min(e_hi, cy * ECHUNK + ECHUNK);
    if (e_lo >= e_hi) return;   // wave-uniform early out

    const int p = (z0r + (lane >> 4)) * NX + x0c + (lane & (XT - 1));
    const float x = grid[3 * p + 0];
    const float z = grid[3 * p + 2];

    const float zrev_full = z * (2.0f * FDEMOD / C_SOUND);
    const float zz = z * z;

    // --- per-angle preamble: txdel + tx phasor P_tx = apo * e^{j*2pi*tq} ---
    float txd[NANG], Pr[NANG], Pi[NANG];
    #pragma unroll
    for (int a = 0; a < NANG; ++a) {
        const float ang = angles[a];
        const float sa = sinf(ang);
        const float ca = cosf(ang);
        txd[a] = (x * sa + z * ca) * FS_C + time_zero[a] * FS;
        const float x_proj = x - z * (sa / ca);
        const float apo = ((x_proj >= ex0 * 1.2f) && (x_proj <= xlimN * 1.2f))
                          ? 1.0f : 0.0f;
        float tq = fmaf(0.25f, txd[a], -zrev_full);
        tq -= floorf(tq);                       // [0,1) revolutions
        Pr[a] = __builtin_amdgcn_cosf(tq) * apo;
        Pi[a] = __builtin_amdgcn_sinf(tq) * apo;
    }

    // Dual accumulator pairs (even/odd e) keep two independent chains
    float ai0 = 0.0f, aq0 = 0.0f, ai1 = 0.0f, aq1 = 0.0f;

    const float* __restrict__ ibase = idata;
    const float* __restrict__ qbase = qdata;

    auto body = [&](int e, float& ai, float& aq) {
        const float ex = ele_pos[3 * e];        // uniform -> scalar load
        const float vx = x - ex;
        const bool accept = z > 2.0f * fabsf(vx);   // exact rx mask

        const float r = sqrtf(fmaf(vx, vx, zz));
        const float rxdel = r * FS_C;

        // rx phasor R = accept * e^{j*2pi*rxq}, ONE sincos shared by 4 angles
        float rxq = 0.25f * rxdel;
        rxq -= floorf(rxq);                     // [0,1) revolutions
        float cr = __builtin_amdgcn_cosf(rxq);
        float sr = __builtin_amdgcn_sinf(rxq);
        cr = accept ? cr : 0.0f;
        sr = accept ? sr : 0.0f;

        #pragma unroll
        for (int a = 0; a < NANG; ++a) {
            const float delays = rxdel + txd[a];
            const float i0f  = floorf(delays);
            const float frac = delays - i0f;
            const int   i0   = (int)i0f;        // proven in [26,1520]

            const size_t off = (((size_t)a * NELEM + e) << 11) + i0;
            const float2 iv = *(const float2*)(ibase + off);
            const float2 qv = *(const float2*)(qbase + off);

            const float ifoc = fmaf(frac, iv.y - iv.x, iv.x);
            const float qfoc = fmaf(frac, qv.y - qv.x, qv.x);

            // full phasor = R * P_tx[a]
            const float ct = cr * Pr[a] - sr * Pi[a];
            const float st = fmaf(sr, Pr[a], cr * Pi[a]);

            ai = fmaf(ifoc, ct, ai);
            ai = fmaf(-qfoc, st, ai);
            aq = fmaf(qfoc, ct, aq);
            aq = fmaf(ifoc, st, aq);
        }
    };

    int e = e_lo;
    #pragma unroll 2
    for (; e + 1 < e_hi; e += 2) {
        body(e,     ai0, aq0);
        body(e + 1, ai1, aq1);
    }
    if (e < e_hi) body(e, ai0, aq0);

    // One coalesced atomic pair per wave (64 consecutive addresses each)
    atomicAdd(&out[p],        ai0 + ai1);
    atomicAdd(&out[NPIX + p], aq0 + aq1);
}

extern "C" void kernel_launch(void* const* d_in, const int* in_sizes, int n_in,
                              void* d_out, int out_size, void* d_ws, size_t ws_size,
                              hipStream_t stream) {
    const float* idata     = (const float*)d_in[0];
    const float* qdata     = (const float*)d_in[1];
    const float* grid      = (const float*)d_in[2];
    const float* angles    = (const float*)d_in[3];
    const float* ele_pos   = (const float*)d_in[4];
    const float* time_zero = (const float*)d_in[5];
    float* out = (float*)d_out;

    // d_out is poisoned before each call; atomics need zeros (graph-safe)
    hipMemsetAsync(out, 0, (size_t)out_size * sizeof(float), stream);

    dim3 block(64, NANG, 1);                 // 4 waves: element chunks
    dim3 gridDim(NXT * NZT, 1, 1);           // 576 blocks (one per tile)
    das_pw_kernel<<<gridDim, block, 0, stream>>>(
        idata, qdata, grid, angles, ele_pos, time_zero, out);
}

// Round 9
// 88.271 us; speedup vs baseline: 1.2965x; 1.2965x over previous
//
#include <hip/hip_runtime.h>
#include <math.h>

// Problem constants (match reference)
#define NANG   4
#define NELEM  128
#define NSAMP  2048
#define NZ     192
#define NX     192
#define NPIX   (NZ * NX)
#define NCHUNK 8
#define ECHUNK (NELEM / NCHUNK)   // 16 elements per chunk
#define XT     16                 // tile: 16 pixels in x ...
#define ZT     4                  // ... by 4 rows in z
#define NXT    (NX / XT)          // 12
#define NZT    (NZ / ZT)          // 48

constexpr float C_SOUND = 1540.0f;
constexpr float FS      = 20832000.0f;
constexpr float FDEMOD  = 5208000.0f;
constexpr float FS_C    = FS / C_SOUND;      // samples per meter

// R9 = R6 (best: 86.1 us) + XCD-aware block swizzle.
// grid = (NCHUNK, NXT*NZT): linear block id = chunk + 8*tile, and the
// dispatcher round-robins blocks over the 8 XCDs -> XCD id == chunk.
// Each chunk's working set (4 ang x 16 elem x 8KB x 2 arrays ~= 1 MB) then
// fits its XCD's private 4MB L2 -> compulsory-only HBM fetches (R8 showed
// 19.6MB FETCH vs 8.4MB payload = cross-XCD duplication), cutting the
// average divergent-gather latency (the measured wall: R5/R6 neutrality
// killed the VALU/instruction-count theories, R7/R8 killed LDS-staging and
// low-TLP trans-sharing).
//
// Carried facts (verified across passing rounds, absmax 0.25):
//  - rx apod == (z > 2|x-ex|) exactly; block-uniform e-interval skip
//  - delays in [26,1520] -> no sample-index clamp needed
//  - FDEMOD/FS == 0.25 -> phase mod 1 via (i0 & 3); v_sin/v_cos take
//    revolutions, |rev| < 1
//  - (s[i0],s[i0+1]) loaded as ONE float2 (dwordx2, unaligned-OK)
//  - reads only d_in (d_ws staging diverged under graph replay in R3)
//  - memset + one coalesced atomicAdd pair per wave on d_out (replay-proven)
__global__ __launch_bounds__(256) void das_pw_kernel(
    const float* __restrict__ idata,     // [NANG][NELEM][NSAMP]
    const float* __restrict__ qdata,     // [NANG][NELEM][NSAMP]
    const float* __restrict__ grid,      // [NPIX][3]
    const float* __restrict__ angles,    // [NANG]
    const float* __restrict__ ele_pos,   // [NELEM][3]
    const float* __restrict__ time_zero, // [NANG]
    float* __restrict__ out)             // [2*NPIX]: idas then qdas (pre-zeroed)
{
    const int lane  = threadIdx.x;       // 0..63 : pixel within tile
    const int a     = threadIdx.y;       // 0..3  : angle (independent wave)
    const int chunk = (int)blockIdx.x;   // 0..7  : element chunk == XCD id
    const int tile  = (int)blockIdx.y;   // 0..575: pixel tile

    const int x0c = (tile % NXT) * XT;
    const int z0r = (tile / NXT) * ZT;

    // Block-uniform geometry (uniform addresses -> scalar loads)
    const float ex0    = ele_pos[0];
    const float inv_pe = 1.0f / (ele_pos[3] - ex0);
    const float xlimN  = ele_pos[3 * (NELEM - 1)];
    const float xminT  = grid[3 * (z0r * NX + x0c)];
    const float xmaxT  = grid[3 * (z0r * NX + x0c + XT - 1)];
    const float zmaxT  = grid[3 * ((z0r + ZT - 1) * NX + x0c) + 2];
    const float half   = 0.5f * zmaxT;

    int e_lo = (int)floorf((xminT - half - ex0) * inv_pe);      // conservative
    int e_hi = (int)ceilf ((xmaxT + half - ex0) * inv_pe) + 1;  // exclusive
    const int c0 = chunk * ECHUNK;
    e_lo = max(e_lo, c0);
    e_hi = min(e_hi, c0 + ECHUNK);
    if (e_lo >= e_hi) return;   // whole chunk outside accept-interval

    const int p = (z0r + (lane >> 4)) * NX + x0c + (lane & (XT - 1));
    const float x = grid[3 * p + 0];
    const float z = grid[3 * p + 2];

    // Per-(pixel,angle) transmit delay & tx apodization
    const float ang = angles[a];
    const float sa = sinf(ang);
    const float ca = cosf(ang);
    const float txdel = (x * sa + z * ca) * FS_C + time_zero[a] * FS;
    const float x_proj = x - z * (sa / ca);
    const bool txapo = (x_proj >= ex0 * 1.2f) && (x_proj <= xlimN * 1.2f);

    const float zrev_full = z * (2.0f * FDEMOD / C_SOUND);
    const float zrev = zrev_full - floorf(zrev_full);
    const float zz = z * z;

    // Dual accumulator pairs keep two independent chains
    float ai0 = 0.0f, aq0 = 0.0f, ai1 = 0.0f, aq1 = 0.0f;

    if (txapo) {
        const float* __restrict__ ib0 = idata + ((size_t)a * NELEM) * NSAMP;
        const float* __restrict__ qb0 = qdata + ((size_t)a * NELEM) * NSAMP;

        auto body = [&](int e, float ex, float& ai, float& aq) {
            const float vx = x - ex;
            const bool accept = z > 2.0f * fabsf(vx);   // exact rx mask

            const float r = sqrtf(fmaf(vx, vx, zz));
            const float delays = fmaf(r, FS_C, txdel);
            const float i0f  = floorf(delays);
            const float frac = delays - i0f;
            const int   i0   = (int)i0f;            // proven in [26,1520]

            // ONE dwordx2 gather per array for the adjacent lerp pair
            const float2 iv = *(const float2*)(ib0 + (e << 11) + i0);
            const float2 qv = *(const float2*)(qb0 + (e << 11) + i0);

            const float ifoc = fmaf(frac, iv.y - iv.x, iv.x);
            const float qfoc = fmaf(frac, qv.y - qv.x, qv.x);

            const float rev = fmaf(0.25f, (float)(i0 & 3) + frac, -zrev);
            float st = __builtin_amdgcn_sinf(rev);  // sin(2*pi*rev)
            float ct = __builtin_amdgcn_cosf(rev);
            st = accept ? st : 0.0f;
            ct = accept ? ct : 0.0f;

            ai = fmaf(ifoc, ct, ai);
            ai = fmaf(-qfoc, st, ai);
            aq = fmaf(qfoc, ct, aq);
            aq = fmaf(ifoc, st, aq);
        };

        // scalar-prefetch element x one iteration ahead
        float exA = ele_pos[3 * e_lo];
        float exB = (e_lo + 1 < e_hi) ? ele_pos[3 * (e_lo + 1)] : 0.0f;
        int e = e_lo;
        for (; e + 1 < e_hi; e += 2) {
            const float exN  = (e + 2 < e_hi) ? ele_pos[3 * (e + 2)] : 0.0f;
            const float exN2 = (e + 3 < e_hi) ? ele_pos[3 * (e + 3)] : 0.0f;
            body(e,     exA, ai0, aq0);
            body(e + 1, exB, ai1, aq1);
            exA = exN;
            exB = exN2;
        }
        if (e < e_hi) body(e, exA, ai0, aq0);
    }

    // One coalesced atomic pair per wave (64 consecutive addresses each)
    atomicAdd(&out[p],        ai0 + ai1);
    atomicAdd(&out[NPIX + p], aq0 + aq1);
}

extern "C" void kernel_launch(void* const* d_in, const int* in_sizes, int n_in,
                              void* d_out, int out_size, void* d_ws, size_t ws_size,
                              hipStream_t stream) {
    const float* idata     = (const float*)d_in[0];
    const float* qdata     = (const float*)d_in[1];
    const float* grid      = (const float*)d_in[2];
    const float* angles    = (const float*)d_in[3];
    const float* ele_pos   = (const float*)d_in[4];
    const float* time_zero = (const float*)d_in[5];
    float* out = (float*)d_out;

    // d_out is poisoned before each call; atomics need zeros (graph-safe)
    hipMemsetAsync(out, 0, (size_t)out_size * sizeof(float), stream);

    // grid.x = chunk (fastest-varying -> XCD id == chunk), grid.y = tile
    dim3 block(64, NANG, 1);
    dim3 gridDim(NCHUNK, NXT * NZT, 1);          // 8 x 576 blocks
    das_pw_kernel<<<gridDim, block, 0, stream>>>(
        idata, qdata, grid, angles, ele_pos, time_zero, out);
}

// Round 10
// 85.329 us; speedup vs baseline: 1.3412x; 1.0345x over previous
//
#include <hip/hip_runtime.h>
#include <math.h>

// Problem constants (match reference)
#define NANG   4
#define NELEM  128
#define NSAMP  2048
#define NZ     192
#define NX     192
#define NPIX   (NZ * NX)
#define NCHUNK 8
#define ECHUNK (NELEM / NCHUNK)   // 16 elements per chunk
#define XT     16                 // tile: 16 pixels in x ...
#define ZT     4                  // ... by 4 rows in z
#define NXT    (NX / XT)          // 12
#define NZT    (NZ / ZT)          // 48

constexpr float C_SOUND = 1540.0f;
constexpr float FS      = 20832000.0f;
constexpr float FDEMOD  = 5208000.0f;
constexpr float FS_C    = FS / C_SOUND;      // samples per meter

// R10 = exact R6 structure (best: 86.1 us) + 4 independent accumulator
// chains with unroll-4 --> 2x per-thread MLP (4 gather pairs in flight).
// Falsification ledger: VALU diet (R5), gather-instr halving (R6-neutral),
// LDS window staging (R7, +7us), angle factorization at low TLP (R8, +28us),
// XCD swizzle (R9, +2us). Remaining untested dimension: in-flight loads per
// thread behind the ~50cyc addr chain + ~250cyc gather latency.
//
// Carried facts (verified across passing rounds, absmax 0.25):
//  - rx apod == (z > 2|x-ex|) exactly; block-uniform e-interval skip
//  - delays in [26,1520] -> no sample-index clamp needed
//  - FDEMOD/FS == 0.25 -> phase mod 1 via (i0 & 3); v_sin/v_cos take
//    revolutions, |rev| < 1
//  - (s[i0],s[i0+1]) loaded as ONE float2 (dwordx2, unaligned-OK)
//  - reads only d_in (d_ws producer->consumer diverges under graph replay:
//    harness re-poison races the captured graph -- NEVER stage through d_ws)
//  - memset + one coalesced atomicAdd pair per wave on d_out (replay-proven)
__global__ __launch_bounds__(256) void das_pw_kernel(
    const float* __restrict__ idata,     // [NANG][NELEM][NSAMP]
    const float* __restrict__ qdata,     // [NANG][NELEM][NSAMP]
    const float* __restrict__ grid,      // [NPIX][3]
    const float* __restrict__ angles,    // [NANG]
    const float* __restrict__ ele_pos,   // [NELEM][3]
    const float* __restrict__ time_zero, // [NANG]
    float* __restrict__ out)             // [2*NPIX]: idas then qdas (pre-zeroed)
{
    const int lane = threadIdx.x;        // 0..63 : pixel within tile
    const int a    = threadIdx.y;        // 0..3  : angle (independent wave)

    const int x0c = ((int)blockIdx.x % NXT) * XT;
    const int z0r = ((int)blockIdx.x / NXT) * ZT;

    // Block-uniform geometry (uniform addresses -> scalar loads)
    const float ex0    = ele_pos[0];
    const float inv_pe = 1.0f / (ele_pos[3] - ex0);
    const float xlimN  = ele_pos[3 * (NELEM - 1)];
    const float xminT  = grid[3 * (z0r * NX + x0c)];
    const float xmaxT  = grid[3 * (z0r * NX + x0c + XT - 1)];
    const float zmaxT  = grid[3 * ((z0r + ZT - 1) * NX + x0c) + 2];
    const float half   = 0.5f * zmaxT;

    int e_lo = (int)floorf((xminT - half - ex0) * inv_pe);      // conservative
    int e_hi = (int)ceilf ((xmaxT + half - ex0) * inv_pe) + 1;  // exclusive
    const int c0 = (int)blockIdx.y * ECHUNK;
    e_lo = max(e_lo, c0);
    e_hi = min(e_hi, c0 + ECHUNK);
    if (e_lo >= e_hi) return;   // whole chunk outside accept-interval

    const int p = (z0r + (lane >> 4)) * NX + x0c + (lane & (XT - 1));
    const float x = grid[3 * p + 0];
    const float z = grid[3 * p + 2];

    // Per-(pixel,angle) transmit delay & tx apodization
    const float ang = angles[a];
    float sa, ca;
    __sincosf(ang, &sa, &ca);
    const float txdel = (x * sa + z * ca) * FS_C + time_zero[a] * FS;
    const float x_proj = x - z * (sa / ca);
    const bool txapo = (x_proj >= ex0 * 1.2f) && (x_proj <= xlimN * 1.2f);

    const float zrev_full = z * (2.0f * FDEMOD / C_SOUND);
    const float zrev = zrev_full - floorf(zrev_full);
    const float zz = z * z;

    // FOUR independent accumulator chains -> 4 gather pairs in flight
    float ai0 = 0.f, aq0 = 0.f, ai1 = 0.f, aq1 = 0.f;
    float ai2 = 0.f, aq2 = 0.f, ai3 = 0.f, aq3 = 0.f;

    if (txapo) {
        const float* __restrict__ ib0 = idata + ((size_t)a * NELEM) * NSAMP;
        const float* __restrict__ qb0 = qdata + ((size_t)a * NELEM) * NSAMP;

        auto body = [&](int e, float& ai, float& aq) {
            const float ex = ele_pos[3 * e];        // uniform -> scalar load
            const float vx = x - ex;
            const bool accept = z > 2.0f * fabsf(vx);   // exact rx mask

            const float r = sqrtf(fmaf(vx, vx, zz));
            const float delays = fmaf(r, FS_C, txdel);
            const float i0f  = floorf(delays);
            const float frac = delays - i0f;
            const int   i0   = (int)i0f;            // proven in [26,1520]

            // ONE dwordx2 gather per array for the adjacent lerp pair
            const float2 iv = *(const float2*)(ib0 + (e << 11) + i0);
            const float2 qv = *(const float2*)(qb0 + (e << 11) + i0);

            const float ifoc = fmaf(frac, iv.y - iv.x, iv.x);
            const float qfoc = fmaf(frac, qv.y - qv.x, qv.x);

            const float rev = fmaf(0.25f, (float)(i0 & 3) + frac, -zrev);
            float st = __builtin_amdgcn_sinf(rev);  // sin(2*pi*rev)
            float ct = __builtin_amdgcn_cosf(rev);
            st = accept ? st : 0.0f;
            ct = accept ? ct : 0.0f;

            ai = fmaf(ifoc, ct, ai);
            ai = fmaf(-qfoc, st, ai);
            aq = fmaf(qfoc, ct, aq);
            aq = fmaf(ifoc, st, aq);
        };

        int e = e_lo;
        for (; e + 3 < e_hi; e += 4) {              // 4-wide MLP groups
            body(e,     ai0, aq0);
            body(e + 1, ai1, aq1);
            body(e + 2, ai2, aq2);
            body(e + 3, ai3, aq3);
        }
        for (; e < e_hi; ++e) body(e, ai0, aq0);    // remainder (<=3)
    }

    // One coalesced atomic pair per wave (64 consecutive addresses each)
    atomicAdd(&out[p],        (ai0 + ai1) + (ai2 + ai3));
    atomicAdd(&out[NPIX + p], (aq0 + aq1) + (aq2 + aq3));
}

extern "C" void kernel_launch(void* const* d_in, const int* in_sizes, int n_in,
                              void* d_out, int out_size, void* d_ws, size_t ws_size,
                              hipStream_t stream) {
    const float* idata     = (const float*)d_in[0];
    const float* qdata     = (const float*)d_in[1];
    const float* grid      = (const float*)d_in[2];
    const float* angles    = (const float*)d_in[3];
    const float* ele_pos   = (const float*)d_in[4];
    const float* time_zero = (const float*)d_in[5];
    float* out = (float*)d_out;

    // d_out is poisoned before each call; atomics need zeros (graph-safe)
    hipMemsetAsync(out, 0, (size_t)out_size * sizeof(float), stream);

    dim3 block(64, NANG, 1);
    dim3 gridDim(NXT * NZT, NCHUNK, 1);          // 576 x 8 blocks (R6 order)
    das_pw_kernel<<<gridDim, block, 0, stream>>>(
        idata, qdata, grid, angles, ele_pos, time_zero, out);
}